// Round 6
// baseline (959.629 us; speedup 1.0000x reference)
//
#include <hip/hip_runtime.h>
#include <hip/hip_bf16.h>

typedef unsigned short u16;

#define BATCH 64
#define SEQ   256
#define CDIM  384
#define NHEAD 6
#define DHEAD 64
#define NROW  16384   // BATCH*SEQ

constexpr float SCALE = 0.051031036307982884f;  // 384^-0.5

__device__ __forceinline__ u16 f2b(float f) {
    __hip_bfloat16 h = __float2bfloat16(f);
    return *reinterpret_cast<u16*>(&h);
}
__device__ __forceinline__ float b2f(u16 v) {
    __hip_bfloat16 h;
    *reinterpret_cast<u16*>(&h) = v;
    return __bfloat162float(h);
}

// ---------------------------------------------------------------------------
// QKV projection, naive tiled VALU (no MFMA). Y[row,i] = sum_j x[row,j]*W[i,j].
// grid (NROW/32, CDIM/64, 3), block 256. z selects (Wk,Wq,Wv)->(K,Q,V).
// Output scattered bf16 to [B,H,T,D]. All math fp32.
// ---------------------------------------------------------------------------
__global__ __launch_bounds__(256) void proj_qkv(
        const float* __restrict__ X, const float* __restrict__ Wk,
        const float* __restrict__ Wq, const float* __restrict__ Wv,
        u16* __restrict__ Kd, u16* __restrict__ Qd, u16* __restrict__ Vd)
{
    __shared__ float xs[32 * CDIM];          // 48 KB
    const int row0 = blockIdx.x * 32;
    const int i0   = blockIdx.y * 64;
    const float* W = (blockIdx.z == 0) ? Wk : (blockIdx.z == 1 ? Wq : Wv);
    u16*         D = (blockIdx.z == 0) ? Kd : (blockIdx.z == 1 ? Qd : Vd);
    const int tid = threadIdx.x;

    // stage x tile: 32 full rows = 12288 contiguous floats
    for (int t = 0; t < 12; ++t) {
        const int e4 = t * 256 + tid;
        *(float4*)(xs + e4 * 4) = *(const float4*)(X + (size_t)row0 * CDIM + e4 * 4);
    }
    __syncthreads();

    const int i  = i0 + (tid & 63);
    const int r0 = (tid >> 6) * 8;           // this thread's 8 rows
    float acc[8] = {};
    for (int j = 0; j < CDIM; j += 4) {
        const float4 w4 = *(const float4*)(W + (size_t)i * CDIM + j);
#pragma unroll
        for (int rr = 0; rr < 8; ++rr) {
            const float4 x4 = *(const float4*)(xs + (r0 + rr) * CDIM + j);
            acc[rr] += x4.x * w4.x + x4.y * w4.y + x4.z * w4.z + x4.w * w4.w;
        }
    }
    const int h = i >> 6, d = i & 63;
#pragma unroll
    for (int rr = 0; rr < 8; ++rr) {
        const int row = row0 + r0 + rr;
        const int b = row >> 8, tq = row & 255;
        D[(size_t)((b * NHEAD + h) * SEQ + tq) * DHEAD + d] = f2b(acc[rr]);
    }
}

// ---------------------------------------------------------------------------
// Naive attention: one block per (b*h), one thread per query row.
// K,V staged fp32 in LDS (broadcast reads -> conflict-free). Online softmax.
// O overwrites this block's own Q rows (each row read+written only by its
// own thread -> no hazard).
// ---------------------------------------------------------------------------
__global__ __launch_bounds__(256) void attn_naive(
        const u16* __restrict__ Kw, const u16* __restrict__ Vw,
        u16* __restrict__ QOw)
{
    __shared__ float Ks[SEQ * DHEAD];        // 64 KB
    __shared__ float Vs[SEQ * DHEAD];        // 64 KB
    const int bh  = blockIdx.x;
    const int tid = threadIdx.x;
    const size_t base = (size_t)bh * SEQ * DHEAD;

    // stage K,V (bf16 -> fp32), 16384 elements each, contiguous
    for (int t = 0; t < 8; ++t) {
        const int e8 = t * 256 + tid;        // 2048 groups of 8
        union { uint4 v; u16 e[8]; } a, b;
        a.v = *(const uint4*)(Kw + base + (size_t)e8 * 8);
        b.v = *(const uint4*)(Vw + base + (size_t)e8 * 8);
#pragma unroll
        for (int j = 0; j < 8; ++j) {
            Ks[e8 * 8 + j] = b2f(a.e[j]);
            Vs[e8 * 8 + j] = b2f(b.e[j]);
        }
    }
    // this thread's Q row -> registers
    float q[64];
    {
        const u16* Qp = QOw + base + (size_t)tid * DHEAD;
#pragma unroll
        for (int t = 0; t < 8; ++t) {
            union { uint4 v; u16 e[8]; } a;
            a.v = *(const uint4*)(Qp + t * 8);
#pragma unroll
            for (int j = 0; j < 8; ++j) q[t * 8 + j] = b2f(a.e[j]);
        }
    }
    __syncthreads();

    float o[64] = {};
    float m = -3.0e38f, l = 0.f;
    for (int k = 0; k <= tid; ++k) {         // causal: keys 0..q
        float dot = 0.f;
#pragma unroll
        for (int d4 = 0; d4 < 16; ++d4) {
            const float4 kv = *(const float4*)(Ks + k * 64 + d4 * 4);
            dot += q[d4*4+0]*kv.x + q[d4*4+1]*kv.y + q[d4*4+2]*kv.z + q[d4*4+3]*kv.w;
        }
        const float s = dot * SCALE;
        if (s > m) {                         // rescale on new max
            const float f = __expf(m - s);   // m=-3e38 -> f=0 (first key)
            l *= f;
#pragma unroll
            for (int d = 0; d < 64; ++d) o[d] *= f;
            m = s;
        }
        const float p = __expf(s - m);
        l += p;
#pragma unroll
        for (int d4 = 0; d4 < 16; ++d4) {
            const float4 vv = *(const float4*)(Vs + k * 64 + d4 * 4);
            o[d4*4+0] += p * vv.x; o[d4*4+1] += p * vv.y;
            o[d4*4+2] += p * vv.z; o[d4*4+3] += p * vv.w;
        }
    }
    const float inv = 1.f / l;
    u16* Op = QOw + base + (size_t)tid * DHEAD;
#pragma unroll
    for (int t = 0; t < 8; ++t) {
        union { uint4 v; u16 e[8]; } a;
#pragma unroll
        for (int j = 0; j < 8; ++j) a.e[j] = f2b(o[t * 8 + j] * inv);
        *(uint4*)(Op + t * 8) = a.v;
    }
}

// ---------------------------------------------------------------------------
// Output projection: out[row,i] = sum_j O[row,j]*Wo[i,j] + bo[i].
// O is bf16 [B,H,T,D] (composite read, feature j = h*64+d). Writes **fp32**
// row-major [16384 x 384] to d_out. grid (NROW/32, CDIM/64), block 256.
// ---------------------------------------------------------------------------
__global__ __launch_bounds__(256) void proj_out(
        const u16* __restrict__ O, const float* __restrict__ Wo,
        const float* __restrict__ bo, float* __restrict__ out)
{
    __shared__ float xs[32 * CDIM];          // 48 KB
    const int row0 = blockIdx.x * 32;
    const int i0   = blockIdx.y * 64;
    const int tid  = threadIdx.x;

    // stage O tile 32x384 (bf16 composite -> fp32 LDS); 8-elem runs never
    // cross a D=64 boundary (384%8==0, 64%8==0)
    for (int t = 0; t < 6; ++t) {
        const int e8 = t * 256 + tid;        // 1536 groups of 8
        const int el = e8 * 8;
        const int r = el / CDIM, c = el % CDIM;
        const int row = row0 + r;
        const int b = row >> 8, tq = row & 255;
        const int h = c >> 6, d = c & 63;
        union { uint4 v; u16 e[8]; } a;
        a.v = *(const uint4*)(O + (size_t)((b * NHEAD + h) * SEQ + tq) * DHEAD + d);
#pragma unroll
        for (int j = 0; j < 8; ++j) xs[el + j] = b2f(a.e[j]);
    }
    __syncthreads();

    const int i  = i0 + (tid & 63);
    const int r0 = (tid >> 6) * 8;
    float acc[8] = {};
    for (int j = 0; j < CDIM; j += 4) {
        const float4 w4 = *(const float4*)(Wo + (size_t)i * CDIM + j);
#pragma unroll
        for (int rr = 0; rr < 8; ++rr) {
            const float4 x4 = *(const float4*)(xs + (r0 + rr) * CDIM + j);
            acc[rr] += x4.x * w4.x + x4.y * w4.y + x4.z * w4.z + x4.w * w4.w;
        }
    }
    const float bb = bo[i];
#pragma unroll
    for (int rr = 0; rr < 8; ++rr) {
        const int row = row0 + r0 + rr;
        out[(size_t)row * CDIM + i] = acc[rr] + bb;   // fp32 output
    }
}

extern "C" void kernel_launch(void* const* d_in, const int* in_sizes, int n_in,
                              void* d_out, int out_size, void* d_ws, size_t ws_size,
                              hipStream_t stream)
{
    const float* x  = (const float*)d_in[0];
    const float* Wk = (const float*)d_in[1];
    const float* Wq = (const float*)d_in[2];
    const float* Wv = (const float*)d_in[3];
    const float* Wo = (const float*)d_in[4];
    const float* bo = (const float*)d_in[5];
    float* out = (float*)d_out;              // fp32 output per reference dtype

    // ws: K + Q(->O in place) + V, bf16 [B,H,T,D], 3 x 12.58 MB = 37.7 MB
    const size_t SZ = (size_t)NROW * CDIM;
    u16* Kw = (u16*)d_ws;
    u16* Qw = Kw + SZ;
    u16* Vw = Qw + SZ;

    proj_qkv<<<dim3(NROW / 32, CDIM / 64, 3), 256, 0, stream>>>(
        x, Wk, Wq, Wv, Kw, Qw, Vw);

    attn_naive<<<dim3(BATCH * NHEAD), 256, 0, stream>>>(Kw, Vw, Qw);

    proj_out<<<dim3(NROW / 32, CDIM / 64), 256, 0, stream>>>(Qw, Wo, bo, out);
}

// Round 7
// 177.819 us; speedup vs baseline: 5.3967x; 5.3967x over previous
//
#include <hip/hip_runtime.h>
#include <hip/hip_bf16.h>

typedef unsigned short u16;
typedef __attribute__((ext_vector_type(8))) short short8;   // 8 bf16 = 4 VGPRs
typedef __attribute__((ext_vector_type(4))) float f32x4;

#define BATCH 64
#define SEQ   256
#define CDIM  384
#define NHEAD 6
#define DHEAD 64
#define NROW  16384   // BATCH*SEQ

constexpr float SCALE = 0.051031036307982884f;  // 384^-0.5

__device__ __forceinline__ f32x4 mfma16(short8 a, short8 b, f32x4 c) {
    return __builtin_amdgcn_mfma_f32_16x16x32_bf16(a, b, c, 0, 0, 0);
}

__device__ __forceinline__ u16 f2b(float f) {
    __hip_bfloat16 h = __float2bfloat16(f);
    return *reinterpret_cast<u16*>(&h);
}

// 8 consecutive fp32 -> 8 bf16, via two float4 vector loads
__device__ __forceinline__ short8 pack8(const float* __restrict__ p) {
    const float4 a = *(const float4*)p;
    const float4 b = *(const float4*)(p + 4);
    short8 r;
    r[0] = (short)f2b(a.x); r[1] = (short)f2b(a.y);
    r[2] = (short)f2b(a.z); r[3] = (short)f2b(a.w);
    r[4] = (short)f2b(b.x); r[5] = (short)f2b(b.y);
    r[6] = (short)f2b(b.z); r[7] = (short)f2b(b.w);
    return r;
}

// ---------------------------------------------------------------------------
// K/V projection: Y = X @ W^T, X fp32 [16384x384], W fp32 [384x384].
// 128x128 tile, BK=32, 4 waves @ 64x64. fp32->bf16 in staging.
// blockIdx.z: 0 -> K (ws), 1 -> V (d_out). Scatter to [B,H,T,D] bf16.
// ---------------------------------------------------------------------------
__global__ __launch_bounds__(256) void gemm_kv(
        const float* __restrict__ X, const float* __restrict__ Wk,
        const float* __restrict__ Wv, u16* __restrict__ Kd, u16* __restrict__ Vd)
{
    __shared__ u16 As[128 * 32];
    __shared__ u16 Bs[128 * 32];

    const int m0 = blockIdx.x * 128;
    const int n0 = blockIdx.y * 128;
    const float* W = (blockIdx.z == 0) ? Wk : Wv;
    u16* D        = (blockIdx.z == 0) ? Kd : Vd;

    const int tid  = threadIdx.x;
    const int lane = tid & 63;
    const int wv   = tid >> 6;
    const int l15  = lane & 15;
    const int q4   = lane >> 4;
    const int wm   = (wv >> 1) * 64;
    const int wn   = (wv & 1) * 64;

    f32x4 acc[4][4] = {};

    for (int kk = 0; kk < CDIM; kk += 32) {
        short8 areg[2], breg[2];
#pragma unroll
        for (int ch = 0; ch < 2; ++ch) {
            const int f = (ch * 256 + tid) * 8;
            const int r = f >> 5;
            const int c = f & 31;
            areg[ch] = pack8(X + (size_t)(m0 + r) * CDIM + kk + c);
            breg[ch] = pack8(W + (size_t)(n0 + r) * CDIM + kk + c);
        }
        __syncthreads();   // previous iteration's readers done
#pragma unroll
        for (int ch = 0; ch < 2; ++ch) {
            const int f = (ch * 256 + tid) * 8;
            *(short8*)(As + f) = areg[ch];
            *(short8*)(Bs + f) = breg[ch];
        }
        __syncthreads();   // stores visible

        short8 af[4], bf[4];
#pragma unroll
        for (int t = 0; t < 4; ++t) {
            af[t] = *(const short8*)(As + (wm + t * 16 + l15) * 32 + q4 * 8);
            bf[t] = *(const short8*)(Bs + (wn + t * 16 + l15) * 32 + q4 * 8);
        }
#pragma unroll
        for (int tm = 0; tm < 4; ++tm)
#pragma unroll
            for (int tn = 0; tn < 4; ++tn)
                acc[tm][tn] = mfma16(af[tm], bf[tn], acc[tm][tn]);
    }

    // C/D layout: col = lane&15, row = (lane>>4)*4 + reg
#pragma unroll
    for (int tm = 0; tm < 4; ++tm) {
#pragma unroll
        for (int tn = 0; tn < 4; ++tn) {
            const int col = n0 + wn + tn * 16 + l15;
#pragma unroll
            for (int r = 0; r < 4; ++r) {
                const int row = m0 + wm + tm * 16 + q4 * 4 + r;
                const int b = row >> 8, t = row & 255;
                const int h = col >> 6, d = col & 63;
                D[(size_t)((b * NHEAD + h) * SEQ + t) * DHEAD + d] = f2b(acc[tm][tn][r]);
            }
        }
    }
}

// ---------------------------------------------------------------------------
// Fused Q-projection + attention. Block = (chunk CH, bh).
// Phase 1: Q_tile[64x64] = x[b, CH*64.., :] @ Wq[h*64.., :]^T (fp32 in).
// Phase 2: S = Q K^T * scale, causal; softmax; O = P V.  O -> ws [B,H,T,D].
// LDS region SA (9216 u16) aliased: Xs/Wqs -> Qbuf -> Kbuf -> Vt.
// ---------------------------------------------------------------------------
template <int CH>
__device__ __forceinline__ void attn_body(
        const float* __restrict__ x, const float* __restrict__ Wq,
        const u16* __restrict__ Kg, const u16* __restrict__ Vg,
        u16* __restrict__ Og, int bh, u16* SA, u16* Pbuf)
{
    constexpr int NKEY = 64 * (CH + 1);
    constexpr int KT   = NKEY / 16;
    constexpr int NPH  = (NKEY + 127) / 128;

    const int tid  = threadIdx.x;
    const int wv   = tid >> 6;
    const int lane = tid & 63;
    const int l15  = lane & 15;
    const int q4   = lane >> 4;
    const int b    = bh / NHEAD;
    const int h    = bh % NHEAD;
    const int bq0  = b * SEQ + CH * 64;        // first x-row of this chunk
    const int qrow0 = CH * 64 + wv * 16;       // wave's first query row
    const int qmax  = qrow0 + 15;

    // ---- Phase 1: Q tile GEMM (64 x 64, K=384) --------------------------
    u16* Xs  = SA;          // 64x32
    u16* Wqs = SA + 2048;   // 64x32
    f32x4 qacc[4] = {};
    for (int kk = 0; kk < CDIM; kk += 32) {
        const int f = tid * 8;          // 2048 elements, 8/thread
        const int r = f >> 5;
        const int c = f & 31;
        short8 xv = pack8(x  + (size_t)(bq0 + r) * CDIM + kk + c);
        short8 wq = pack8(Wq + (size_t)(h * 64 + r) * CDIM + kk + c);
        __syncthreads();
        *(short8*)(Xs + f)  = xv;
        *(short8*)(Wqs + f) = wq;
        __syncthreads();
        short8 xa = *(const short8*)(Xs + (wv * 16 + l15) * 32 + q4 * 8);
#pragma unroll
        for (int tn = 0; tn < 4; ++tn) {
            short8 wb = *(const short8*)(Wqs + (tn * 16 + l15) * 32 + q4 * 8);
            qacc[tn] = mfma16(xa, wb, qacc[tn]);
        }
    }
    __syncthreads();

    // Q tile -> LDS (stride 72), then A-frags to registers
    u16* Qbuf = SA;                     // 64x72
#pragma unroll
    for (int tn = 0; tn < 4; ++tn)
#pragma unroll
        for (int r = 0; r < 4; ++r)
            Qbuf[(wv * 16 + q4 * 4 + r) * 72 + tn * 16 + l15] = f2b(qacc[tn][r]);
    __syncthreads();
    short8 aq[2];
#pragma unroll
    for (int ks = 0; ks < 2; ++ks)
        aq[ks] = *(const short8*)(Qbuf + (wv * 16 + l15) * 72 + ks * 32 + q4 * 8);
    __syncthreads();                    // aq in regs; SA free

    // ---- Phase 2a: S = Q K^T * scale, causal ----------------------------
    u16* Kbuf = SA;                     // 128x72
    f32x4 s[KT];
#pragma unroll
    for (int ph = 0; ph < NPH; ++ph) {
        const int rows = (NKEY - ph * 128) < 128 ? (NKEY - ph * 128) : 128;
        for (int it = 0; it < rows / 32; ++it) {
            const int r  = it * 32 + (tid >> 3);
            const int d0 = (tid & 7) * 8;
            *(uint4*)(Kbuf + r * 72 + d0) =
                *(const uint4*)(Kg + (size_t)(bh * SEQ + ph * 128 + r) * DHEAD + d0);
        }
        __syncthreads();
#pragma unroll
        for (int t = 0; t < rows / 16; ++t) {
            const int gt = ph * 8 + t;
            if (gt * 16 <= qmax) {
                f32x4 z = {0.f, 0.f, 0.f, 0.f};
#pragma unroll
                for (int ks = 0; ks < 2; ++ks) {
                    short8 bk = *(const short8*)(Kbuf + (t * 16 + l15) * 72
                                                 + ks * 32 + q4 * 8);
                    z = mfma16(aq[ks], bk, z);
                }
                const int kc = gt * 16 + l15;
#pragma unroll
                for (int r = 0; r < 4; ++r) {
                    float v = z[r] * SCALE;
                    if (kc > qrow0 + q4 * 4 + r) v = -1e30f;
                    z[r] = v;
                }
                s[gt] = z;
            } else {
                f32x4 neg = {-1e30f, -1e30f, -1e30f, -1e30f};
                s[gt] = neg;
            }
        }
        __syncthreads();
    }

    // ---- softmax --------------------------------------------------------
    float mx[4], sm[4], rs[4];
#pragma unroll
    for (int r = 0; r < 4; ++r) {
        float m = -1e30f;
#pragma unroll
        for (int t = 0; t < KT; ++t) m = fmaxf(m, s[t][r]);
#pragma unroll
        for (int off = 1; off < 16; off <<= 1)
            m = fmaxf(m, __shfl_xor(m, off, 16));
        mx[r] = m;
        sm[r] = 0.f;
    }
#pragma unroll
    for (int t = 0; t < KT; ++t)
#pragma unroll
        for (int r = 0; r < 4; ++r) {
            float p = __expf(s[t][r] - mx[r]);
            s[t][r] = p;
            sm[r] += p;
        }
#pragma unroll
    for (int r = 0; r < 4; ++r) {
#pragma unroll
        for (int off = 1; off < 16; off <<= 1)
            sm[r] += __shfl_xor(sm[r], off, 16);
        rs[r] = 1.f / sm[r];
    }

    // ---- Phase 2b: O = P V ----------------------------------------------
    u16* Vt = SA;                       // 64 x 136
    u16* Pw = Pbuf + wv * 16 * 40;      // per-wave 16x32 P block
    f32x4 o[4] = {};
#pragma unroll
    for (int ph = 0; ph < NPH; ++ph) {
        const int rows = (NKEY - ph * 128) < 128 ? (NKEY - ph * 128) : 128;
        for (int it = 0; it < rows / 32; ++it) {
            const int r  = it * 32 + (tid >> 3);
            const int d0 = (tid & 7) * 8;
            union { uint4 v; u16 e[8]; } tmp;
            tmp.v = *(const uint4*)(Vg + (size_t)(bh * SEQ + ph * 128 + r) * DHEAD + d0);
#pragma unroll
            for (int j = 0; j < 8; ++j) Vt[(d0 + j) * 136 + r] = tmp.e[j];
        }
        __syncthreads();
#pragma unroll
        for (int ks = 0; ks < rows / 32; ++ks) {
            const int gks = ph * 4 + ks;
            if (gks * 32 <= qmax) {
#pragma unroll
                for (int tt = 0; tt < 2; ++tt) {
                    const int gt = gks * 2 + tt;
#pragma unroll
                    for (int r = 0; r < 4; ++r)
                        Pw[(q4 * 4 + r) * 40 + tt * 16 + l15] = f2b(s[gt][r]);
                }
                asm volatile("s_waitcnt lgkmcnt(0)" ::: "memory");
                short8 ap = *(const short8*)(Pw + l15 * 40 + q4 * 8);
#pragma unroll
                for (int tn = 0; tn < 4; ++tn) {
                    short8 bv = *(const short8*)(Vt + (tn * 16 + l15) * 136
                                                 + ks * 32 + q4 * 8);
                    o[tn] = mfma16(ap, bv, o[tn]);
                }
            }
        }
        __syncthreads();
    }

    // ---- store O -> ws [B,H,T,D] ----------------------------------------
#pragma unroll
    for (int tn = 0; tn < 4; ++tn) {
        const int d = tn * 16 + l15;
#pragma unroll
        for (int r = 0; r < 4; ++r) {
            const int qr = qrow0 + q4 * 4 + r;
            Og[(size_t)(bh * SEQ + qr) * DHEAD + d] = f2b(o[tn][r] * rs[r]);
        }
    }
}

__global__ __launch_bounds__(256) void attn_kernel(
        const float* __restrict__ x, const float* __restrict__ Wq,
        const u16* __restrict__ Kg, const u16* __restrict__ Vg,
        u16* __restrict__ Og)
{
    __shared__ u16 SA[128 * 72];        // 18 KB, phase-aliased
    __shared__ u16 Pbuf[4 * 16 * 40];   //  5 KB
    const int bh = blockIdx.y;
    switch (blockIdx.x) {
        case 0: attn_body<0>(x, Wq, Kg, Vg, Og, bh, SA, Pbuf); break;
        case 1: attn_body<1>(x, Wq, Kg, Vg, Og, bh, SA, Pbuf); break;
        case 2: attn_body<2>(x, Wq, Kg, Vg, Og, bh, SA, Pbuf); break;
        default: attn_body<3>(x, Wq, Kg, Vg, Og, bh, SA, Pbuf); break;
    }
}

// ---------------------------------------------------------------------------
// Output projection: out = O @ Wo^T + bo. O bf16 [B,H,T,D] (composite read),
// Wo/bo fp32. Writes **fp32** row-major [16384x384] to d_out.
// ---------------------------------------------------------------------------
__global__ __launch_bounds__(256) void gemm_out(
        const u16* __restrict__ O, const float* __restrict__ Wo,
        const float* __restrict__ bias, float* __restrict__ out)
{
    __shared__ u16 As[128 * 32];
    __shared__ u16 Bs[128 * 32];

    const int m0 = blockIdx.x * 128;
    const int n0 = blockIdx.y * 128;

    const int tid  = threadIdx.x;
    const int lane = tid & 63;
    const int wv   = tid >> 6;
    const int l15  = lane & 15;
    const int q4   = lane >> 4;
    const int wm   = (wv >> 1) * 64;
    const int wn   = (wv & 1) * 64;

    f32x4 acc[4][4] = {};

    for (int kk = 0; kk < CDIM; kk += 32) {
        uint4 areg[2];
        short8 breg[2];
#pragma unroll
        for (int ch = 0; ch < 2; ++ch) {
            const int f = (ch * 256 + tid) * 8;
            const int r = f >> 5;
            const int c = f & 31;
            const int row = m0 + r;
            const int b = row >> 8, t = row & 255;
            const int k = kk + c;
            const int hh = k >> 6, dd = k & 63;
            areg[ch] = *(const uint4*)(O +
                (size_t)((b * NHEAD + hh) * SEQ + t) * DHEAD + dd);
            breg[ch] = pack8(Wo + (size_t)(n0 + r) * CDIM + kk + c);
        }
        __syncthreads();
#pragma unroll
        for (int ch = 0; ch < 2; ++ch) {
            const int f = (ch * 256 + tid) * 8;
            *(uint4*)(As + f)  = areg[ch];
            *(short8*)(Bs + f) = breg[ch];
        }
        __syncthreads();

        short8 af[4], bf[4];
#pragma unroll
        for (int t = 0; t < 4; ++t) {
            af[t] = *(const short8*)(As + (wm + t * 16 + l15) * 32 + q4 * 8);
            bf[t] = *(const short8*)(Bs + (wn + t * 16 + l15) * 32 + q4 * 8);
        }
#pragma unroll
        for (int tm = 0; tm < 4; ++tm)
#pragma unroll
            for (int tn = 0; tn < 4; ++tn)
                acc[tm][tn] = mfma16(af[tm], bf[tn], acc[tm][tn]);
    }

#pragma unroll
    for (int tm = 0; tm < 4; ++tm) {
#pragma unroll
        for (int tn = 0; tn < 4; ++tn) {
            const int col = n0 + wn + tn * 16 + l15;
            const float bb = bias[col];
#pragma unroll
            for (int r = 0; r < 4; ++r) {
                const int row = m0 + wm + tm * 16 + q4 * 4 + r;
                out[(size_t)row * CDIM + col] = acc[tm][tn][r] + bb;  // fp32
            }
        }
    }
}

extern "C" void kernel_launch(void* const* d_in, const int* in_sizes, int n_in,
                              void* d_out, int out_size, void* d_ws, size_t ws_size,
                              hipStream_t stream)
{
    const float* x  = (const float*)d_in[0];
    const float* Wk = (const float*)d_in[1];
    const float* Wq = (const float*)d_in[2];
    const float* Wv = (const float*)d_in[3];
    const float* Wo = (const float*)d_in[4];
    const float* bo = (const float*)d_in[5];
    float* out = (float*)d_out;              // fp32 output

    // ws: K + O bf16 [B,H,T,D], 25.2 MB. V scratch in d_out (bf16, 12.6 MB
    // of the 25.2 MB fp32 buffer; dead before gemm_out overwrites).
    const size_t SZ = (size_t)NROW * CDIM;
    u16* Kw = (u16*)d_ws;
    u16* Ow = Kw + SZ;
    u16* Vw = (u16*)d_out;

    dim3 g1(NROW / 128, CDIM / 128, 2);
    gemm_kv<<<g1, 256, 0, stream>>>(x, Wk, Wv, Kw, Vw);

    dim3 g2(4, BATCH * NHEAD);
    attn_kernel<<<g2, 256, 0, stream>>>(x, Wq, Kw, Vw, Ow);

    dim3 g3(NROW / 128, CDIM / 128, 1);
    gemm_out<<<g3, 256, 0, stream>>>(Ow, Wo, bo, out);
}

// Round 8
// 168.755 us; speedup vs baseline: 5.6865x; 1.0537x over previous
//
#include <hip/hip_runtime.h>
#include <hip/hip_bf16.h>

typedef unsigned short u16;
typedef __attribute__((ext_vector_type(8))) short short8;   // 8 bf16 = 4 VGPRs
typedef __attribute__((ext_vector_type(4))) float f32x4;

#define BATCH 64
#define SEQ   256
#define CDIM  384
#define NHEAD 6
#define DHEAD 64
#define NROW  16384   // BATCH*SEQ

constexpr float SCALE = 0.051031036307982884f;  // 384^-0.5

__device__ __forceinline__ f32x4 mfma16(short8 a, short8 b, f32x4 c) {
    return __builtin_amdgcn_mfma_f32_16x16x32_bf16(a, b, c, 0, 0, 0);
}

__device__ __forceinline__ u16 f2b(float f) {
    __hip_bfloat16 h = __float2bfloat16(f);
    return *reinterpret_cast<u16*>(&h);
}

// 8 consecutive fp32 -> 8 bf16 (two float4 vector loads)
__device__ __forceinline__ short8 pack8(const float* __restrict__ p) {
    const float4 a = *(const float4*)p;
    const float4 b = *(const float4*)(p + 4);
    short8 r;
    r[0] = (short)f2b(a.x); r[1] = (short)f2b(a.y);
    r[2] = (short)f2b(a.z); r[3] = (short)f2b(a.w);
    r[4] = (short)f2b(b.x); r[5] = (short)f2b(b.y);
    r[6] = (short)f2b(b.z); r[7] = (short)f2b(b.w);
    return r;
}

// ---------------------------------------------------------------------------
// QKV projection: Y = X @ W^T. 128x128 tile, BK=32, 4 waves @ 64x64.
// grid (3, 128, 3): x = n-tile (fast -> consecutive blocks share the x slab),
// y = m-tile, z selects weight/output:
//   z=0: K -> ws  [B,H,T,D] bf16
//   z=1: V -> out [B,H,D,T] bf16 (TRANSPOSED via LDS epilogue)
//   z=2: Q -> ws  [B,H,T,D] bf16
// ---------------------------------------------------------------------------
__global__ __launch_bounds__(256) void gemm_qkv(
        const float* __restrict__ X, const float* __restrict__ Wk,
        const float* __restrict__ Wv, const float* __restrict__ Wq,
        u16* __restrict__ Kd, u16* __restrict__ VTd, u16* __restrict__ Qd)
{
    __shared__ u16 SMEM[17408];   // 34 KB: As(4096)+Bs(4096) | T(128x136)
    u16* As = SMEM;
    u16* Bs = SMEM + 4096;

    const int n0 = blockIdx.x * 128;
    const int m0 = blockIdx.y * 128;
    const int z  = blockIdx.z;
    const float* W = (z == 0) ? Wk : (z == 1 ? Wv : Wq);

    const int tid  = threadIdx.x;
    const int lane = tid & 63;
    const int wv   = tid >> 6;
    const int l15  = lane & 15;
    const int q4   = lane >> 4;
    const int wm   = (wv >> 1) * 64;
    const int wn   = (wv & 1) * 64;

    f32x4 acc[4][4] = {};

    for (int kk = 0; kk < CDIM; kk += 32) {
        short8 areg[2], breg[2];
#pragma unroll
        for (int ch = 0; ch < 2; ++ch) {
            const int f = (ch * 256 + tid) * 8;
            const int r = f >> 5;
            const int c = f & 31;
            areg[ch] = pack8(X + (size_t)(m0 + r) * CDIM + kk + c);
            breg[ch] = pack8(W + (size_t)(n0 + r) * CDIM + kk + c);
        }
        __syncthreads();
#pragma unroll
        for (int ch = 0; ch < 2; ++ch) {
            const int f = (ch * 256 + tid) * 8;
            *(short8*)(As + f) = areg[ch];
            *(short8*)(Bs + f) = breg[ch];
        }
        __syncthreads();

        short8 af[4], bf[4];
#pragma unroll
        for (int t = 0; t < 4; ++t) {
            af[t] = *(const short8*)(As + (wm + t * 16 + l15) * 32 + q4 * 8);
            bf[t] = *(const short8*)(Bs + (wn + t * 16 + l15) * 32 + q4 * 8);
        }
#pragma unroll
        for (int tm = 0; tm < 4; ++tm)
#pragma unroll
            for (int tn = 0; tn < 4; ++tn)
                acc[tm][tn] = mfma16(af[tm], bf[tn], acc[tm][tn]);
    }

    if (z != 1) {
        // ---- scatter epilogue to [B,H,T,D] ------------------------------
        u16* D = (z == 0) ? Kd : Qd;
#pragma unroll
        for (int tm = 0; tm < 4; ++tm)
#pragma unroll
            for (int tn = 0; tn < 4; ++tn) {
                const int col = n0 + wn + tn * 16 + l15;
#pragma unroll
                for (int r = 0; r < 4; ++r) {
                    const int row = m0 + wm + tm * 16 + q4 * 4 + r;
                    const int b = row >> 8, t = row & 255;
                    const int h = col >> 6, d = col & 63;
                    D[(size_t)((b * NHEAD + h) * SEQ + t) * DHEAD + d] =
                        f2b(acc[tm][tn][r]);
                }
            }
    } else {
        // ---- transpose epilogue: V^T [B,H,D,T] --------------------------
        __syncthreads();                  // all waves done with As/Bs
        u16* T = SMEM;                    // [128 feat][136] (row = feature)
#pragma unroll
        for (int tm = 0; tm < 4; ++tm)
#pragma unroll
            for (int tn = 0; tn < 4; ++tn) {
                const int cl = wn + tn * 16 + l15;          // feature-local
#pragma unroll
                for (int r = 0; r < 4; ++r) {
                    const int rl = wm + tm * 16 + q4 * 4 + r; // t-local
                    T[cl * 136 + rl] = f2b(acc[tm][tn][r]);
                }
            }
        __syncthreads();
        const int b  = m0 >> 8;
        const int t0 = m0 & 255;
        const int fl = tid >> 1;          // feature-local 0..127
        const int hf = tid & 1;           // which 64-t half
        const int fg = n0 + fl;
        const int h  = fg >> 6, d = fg & 63;
        u16* dst = VTd + ((size_t)(b * NHEAD + h) * DHEAD + d) * SEQ + t0 + hf * 64;
        const u16* src = T + fl * 136 + hf * 64;
#pragma unroll
        for (int j = 0; j < 8; ++j)
            *(uint4*)(dst + j * 8) = *(const uint4*)(src + j * 8);
    }
}

// ---------------------------------------------------------------------------
// Attention: block = (chunk CH, bh). 64 query rows, causal keys [0,64(CH+1)).
// Q read directly as bf16 A-frags from ws. K staged [key][72]; V^T staged
// [d][136] via coalesced uint4 (no scalar transpose -> no 8-way conflicts).
// Full score row in registers; O -> ws [B,H,T,D].
// ---------------------------------------------------------------------------
template <int CH>
__device__ __forceinline__ void attn_body(
        const u16* __restrict__ Qg, const u16* __restrict__ Kg,
        const u16* __restrict__ VTg, u16* __restrict__ Og, int bh,
        u16* SA /*9216 u16*/, u16* Pbuf /*4x16x40*/)
{
    constexpr int NKEY = 64 * (CH + 1);
    constexpr int KT   = NKEY / 16;
    constexpr int NPH  = (NKEY + 127) / 128;

    const int tid  = threadIdx.x;
    const int wv   = tid >> 6;
    const int lane = tid & 63;
    const int l15  = lane & 15;
    const int q4   = lane >> 4;
    const int qrow0 = CH * 64 + wv * 16;
    const int qmax  = qrow0 + 15;

    // Q A-frags straight from global [B,H,T,D]
    short8 aq[2];
#pragma unroll
    for (int ks = 0; ks < 2; ++ks)
        aq[ks] = *(const short8*)(Qg + (size_t)(bh * SEQ + qrow0 + l15) * DHEAD
                                     + ks * 32 + q4 * 8);

    // ---- S = Q K^T * scale, causal --------------------------------------
    u16* Kbuf = SA;                      // [128][72]
    f32x4 s[KT];
#pragma unroll
    for (int ph = 0; ph < NPH; ++ph) {
        const int rows = (NKEY - ph * 128) < 128 ? (NKEY - ph * 128) : 128;
        for (int it = 0; it < rows / 32; ++it) {
            const int r  = it * 32 + (tid >> 3);
            const int d0 = (tid & 7) * 8;
            *(uint4*)(Kbuf + r * 72 + d0) =
                *(const uint4*)(Kg + (size_t)(bh * SEQ + ph * 128 + r) * DHEAD + d0);
        }
        __syncthreads();
#pragma unroll
        for (int t = 0; t < rows / 16; ++t) {
            const int gt = ph * 8 + t;
            if (gt * 16 <= qmax) {
                f32x4 z = {0.f, 0.f, 0.f, 0.f};
#pragma unroll
                for (int ks = 0; ks < 2; ++ks) {
                    short8 bk = *(const short8*)(Kbuf + (t * 16 + l15) * 72
                                                 + ks * 32 + q4 * 8);
                    z = mfma16(aq[ks], bk, z);
                }
                const int kc = gt * 16 + l15;
#pragma unroll
                for (int r = 0; r < 4; ++r) {
                    float v = z[r] * SCALE;
                    if (kc > qrow0 + q4 * 4 + r) v = -1e30f;
                    z[r] = v;
                }
                s[gt] = z;
            } else {
                f32x4 neg = {-1e30f, -1e30f, -1e30f, -1e30f};
                s[gt] = neg;
            }
        }
        __syncthreads();
    }

    // ---- softmax --------------------------------------------------------
    float mx[4], sm[4], rs[4];
#pragma unroll
    for (int r = 0; r < 4; ++r) {
        float m = -1e30f;
#pragma unroll
        for (int t = 0; t < KT; ++t) m = fmaxf(m, s[t][r]);
#pragma unroll
        for (int off = 1; off < 16; off <<= 1)
            m = fmaxf(m, __shfl_xor(m, off, 16));
        mx[r] = m;
        sm[r] = 0.f;
    }
#pragma unroll
    for (int t = 0; t < KT; ++t)
#pragma unroll
        for (int r = 0; r < 4; ++r) {
            float p = __expf(s[t][r] - mx[r]);
            s[t][r] = p;
            sm[r] += p;
        }
#pragma unroll
    for (int r = 0; r < 4; ++r) {
#pragma unroll
        for (int off = 1; off < 16; off <<= 1)
            sm[r] += __shfl_xor(sm[r], off, 16);
        rs[r] = 1.f / sm[r];
    }

    // ---- O = P V (V^T staged coalesced) ---------------------------------
    u16* Vt = SA;                        // [64 d][136]
    u16* Pw = Pbuf + wv * 16 * 40;
    f32x4 o[4] = {};
#pragma unroll
    for (int ph = 0; ph < NPH; ++ph) {
        const int rows = (NKEY - ph * 128) < 128 ? (NKEY - ph * 128) : 128;
        const int cpr  = rows >> 3;      // uint4 chunks per d-row (8 or 16)
#pragma unroll
        for (int it = 0; it < 4; ++it) { // up to 4; guarded below
            if (it < cpr / 4) {
                const int flat = it * 256 + tid;
                const int rd = flat / cpr;
                const int kc = (flat - rd * cpr) * 8;
                *(uint4*)(Vt + rd * 136 + kc) =
                    *(const uint4*)(VTg + ((size_t)bh * DHEAD + rd) * SEQ
                                        + ph * 128 + kc);
            }
        }
        __syncthreads();
#pragma unroll
        for (int ks = 0; ks < rows / 32; ++ks) {
            const int gks = ph * 4 + ks;
            if (gks * 32 <= qmax) {
#pragma unroll
                for (int tt = 0; tt < 2; ++tt) {
                    const int gt = gks * 2 + tt;
#pragma unroll
                    for (int r = 0; r < 4; ++r)
                        Pw[(q4 * 4 + r) * 40 + tt * 16 + l15] = f2b(s[gt][r]);
                }
                asm volatile("s_waitcnt lgkmcnt(0)" ::: "memory");
                short8 ap = *(const short8*)(Pw + l15 * 40 + q4 * 8);
#pragma unroll
                for (int tn = 0; tn < 4; ++tn) {
                    short8 bv = *(const short8*)(Vt + (tn * 16 + l15) * 136
                                                 + ks * 32 + q4 * 8);
                    o[tn] = mfma16(ap, bv, o[tn]);
                }
            }
        }
        __syncthreads();
    }

    // ---- store O -> ws [B,H,T,D] ----------------------------------------
#pragma unroll
    for (int tn = 0; tn < 4; ++tn) {
        const int d = tn * 16 + l15;
#pragma unroll
        for (int r = 0; r < 4; ++r) {
            const int qr = qrow0 + q4 * 4 + r;
            Og[(size_t)(bh * SEQ + qr) * DHEAD + d] = f2b(o[tn][r] * rs[r]);
        }
    }
}

__global__ __launch_bounds__(256) void attn_kernel(
        const u16* __restrict__ Qg, const u16* __restrict__ Kg,
        const u16* __restrict__ VTg, u16* __restrict__ Og)
{
    __shared__ u16 SA[128 * 72];        // 18 KB, phase-aliased (Kbuf / Vt)
    __shared__ u16 Pbuf[4 * 16 * 40];   //  5 KB
    const int bh = blockIdx.y;
    switch (blockIdx.x) {
        case 0: attn_body<0>(Qg, Kg, VTg, Og, bh, SA, Pbuf); break;
        case 1: attn_body<1>(Qg, Kg, VTg, Og, bh, SA, Pbuf); break;
        case 2: attn_body<2>(Qg, Kg, VTg, Og, bh, SA, Pbuf); break;
        default: attn_body<3>(Qg, Kg, VTg, Og, bh, SA, Pbuf); break;
    }
}

// ---------------------------------------------------------------------------
// Output projection: out = O @ Wo^T + bo. O bf16 [B,H,T,D] (composite read),
// Wo/bo fp32. Writes fp32 row-major [16384x384] to d_out.
// ---------------------------------------------------------------------------
__global__ __launch_bounds__(256) void gemm_out(
        const u16* __restrict__ O, const float* __restrict__ Wo,
        const float* __restrict__ bias, float* __restrict__ out)
{
    __shared__ u16 As[128 * 32];
    __shared__ u16 Bs[128 * 32];

    const int m0 = blockIdx.y * 128;
    const int n0 = blockIdx.x * 128;

    const int tid  = threadIdx.x;
    const int lane = tid & 63;
    const int wv   = tid >> 6;
    const int l15  = lane & 15;
    const int q4   = lane >> 4;
    const int wm   = (wv >> 1) * 64;
    const int wn   = (wv & 1) * 64;

    f32x4 acc[4][4] = {};

    for (int kk = 0; kk < CDIM; kk += 32) {
        uint4 areg[2];
        short8 breg[2];
#pragma unroll
        for (int ch = 0; ch < 2; ++ch) {
            const int f = (ch * 256 + tid) * 8;
            const int r = f >> 5;
            const int c = f & 31;
            const int row = m0 + r;
            const int b = row >> 8, t = row & 255;
            const int k = kk + c;
            const int hh = k >> 6, dd = k & 63;
            areg[ch] = *(const uint4*)(O +
                (size_t)((b * NHEAD + hh) * SEQ + t) * DHEAD + dd);
            breg[ch] = pack8(Wo + (size_t)(n0 + r) * CDIM + kk + c);
        }
        __syncthreads();
#pragma unroll
        for (int ch = 0; ch < 2; ++ch) {
            const int f = (ch * 256 + tid) * 8;
            *(uint4*)(As + f)  = areg[ch];
            *(short8*)(Bs + f) = breg[ch];
        }
        __syncthreads();

        short8 af[4], bf[4];
#pragma unroll
        for (int t = 0; t < 4; ++t) {
            af[t] = *(const short8*)(As + (wm + t * 16 + l15) * 32 + q4 * 8);
            bf[t] = *(const short8*)(Bs + (wn + t * 16 + l15) * 32 + q4 * 8);
        }
#pragma unroll
        for (int tm = 0; tm < 4; ++tm)
#pragma unroll
            for (int tn = 0; tn < 4; ++tn)
                acc[tm][tn] = mfma16(af[tm], bf[tn], acc[tm][tn]);
    }

#pragma unroll
    for (int tm = 0; tm < 4; ++tm) {
#pragma unroll
        for (int tn = 0; tn < 4; ++tn) {
            const int col = n0 + wn + tn * 16 + l15;
            const float bb = bias[col];
#pragma unroll
            for (int r = 0; r < 4; ++r) {
                const int row = m0 + wm + tm * 16 + q4 * 4 + r;
                out[(size_t)row * CDIM + col] = acc[tm][tn][r] + bb;  // fp32
            }
        }
    }
}

extern "C" void kernel_launch(void* const* d_in, const int* in_sizes, int n_in,
                              void* d_out, int out_size, void* d_ws, size_t ws_size,
                              hipStream_t stream)
{
    const float* x  = (const float*)d_in[0];
    const float* Wk = (const float*)d_in[1];
    const float* Wq = (const float*)d_in[2];
    const float* Wv = (const float*)d_in[3];
    const float* Wo = (const float*)d_in[4];
    const float* bo = (const float*)d_in[5];
    float* out = (float*)d_out;              // fp32 output

    // ws: K + Q(->O in place is NOT used; O separate) -> K + Q + O bf16,
    // 3 x 12.6 MB = 37.7 MB (proven-safe footprint from R6).
    const size_t SZ = (size_t)NROW * CDIM;
    u16* Kw  = (u16*)d_ws;
    u16* Qw  = Kw + SZ;
    u16* Ow  = Qw + SZ;
    u16* VTw = (u16*)d_out;   // V^T [B,H,D,T] scratch in d_out (dead before gemm_out)

    dim3 g1(CDIM / 128, NROW / 128, 3);
    gemm_qkv<<<g1, 256, 0, stream>>>(x, Wk, Wv, Wq, Kw, VTw, Qw);

    dim3 g2(4, BATCH * NHEAD);
    attn_kernel<<<g2, 256, 0, stream>>>(Qw, Kw, VTw, Ow);

    dim3 g3(CDIM / 128, NROW / 128);
    gemm_out<<<g3, 256, 0, stream>>>(Ow, Wo, bo, out);
}

// Round 9
// 157.377 us; speedup vs baseline: 6.0976x; 1.0723x over previous
//
#include <hip/hip_runtime.h>
#include <hip/hip_bf16.h>

typedef unsigned short u16;
typedef __attribute__((ext_vector_type(8))) short short8;   // 8 bf16 = 4 VGPRs
typedef __attribute__((ext_vector_type(4))) float f32x4;

#define BATCH 64
#define SEQ   256
#define CDIM  384
#define NHEAD 6
#define DHEAD 64
#define NROW  16384   // BATCH*SEQ

constexpr float SCALE = 0.051031036307982884f;  // 384^-0.5

__device__ __forceinline__ f32x4 mfma16(short8 a, short8 b, f32x4 c) {
    return __builtin_amdgcn_mfma_f32_16x16x32_bf16(a, b, c, 0, 0, 0);
}

__device__ __forceinline__ u16 f2b(float f) {
    __hip_bfloat16 h = __float2bfloat16(f);
    return *reinterpret_cast<u16*>(&h);
}

__device__ __forceinline__ void gload_lds16(const u16* g, u16* l) {
    __builtin_amdgcn_global_load_lds(
        (const __attribute__((address_space(1))) void*)g,
        (__attribute__((address_space(3))) void*)l, 16, 0, 0);
}

// ---------------------------------------------------------------------------
// fp32 -> bf16 conversion, 8 elems/thread. n must be a multiple of 2048.
// ---------------------------------------------------------------------------
__global__ __launch_bounds__(256) void cvt_x(
        const float* __restrict__ s, u16* __restrict__ d)
{
    const int i = (blockIdx.x * 256 + threadIdx.x) * 8;
    const float4 a = *(const float4*)(s + i);
    const float4 b = *(const float4*)(s + i + 4);
    short8 r;
    r[0] = (short)f2b(a.x); r[1] = (short)f2b(a.y);
    r[2] = (short)f2b(a.z); r[3] = (short)f2b(a.w);
    r[4] = (short)f2b(b.x); r[5] = (short)f2b(b.y);
    r[6] = (short)f2b(b.z); r[7] = (short)f2b(b.w);
    *(short8*)(d + i) = r;
}

__global__ __launch_bounds__(256) void cvt_w(
        const float* __restrict__ w0, const float* __restrict__ w1,
        const float* __restrict__ w2, const float* __restrict__ w3,
        u16* __restrict__ d0, u16* __restrict__ d1,
        u16* __restrict__ d2, u16* __restrict__ d3)
{
    const int z = blockIdx.y;
    const float* s = (z == 0) ? w0 : (z == 1) ? w1 : (z == 2) ? w2 : w3;
    u16*         d = (z == 0) ? d0 : (z == 1) ? d1 : (z == 2) ? d2 : d3;
    const int i = (blockIdx.x * 256 + threadIdx.x) * 8;
    const float4 a = *(const float4*)(s + i);
    const float4 b = *(const float4*)(s + i + 4);
    short8 r;
    r[0] = (short)f2b(a.x); r[1] = (short)f2b(a.y);
    r[2] = (short)f2b(a.z); r[3] = (short)f2b(a.w);
    r[4] = (short)f2b(b.x); r[5] = (short)f2b(b.y);
    r[6] = (short)f2b(b.z); r[7] = (short)f2b(b.w);
    *(short8*)(d + i) = r;
}

// ---------------------------------------------------------------------------
// QKV projection (all-bf16): Y = X @ W^T. 128x128 tile, BK=32, 4 waves @
// 64x64. global_load_lds(16B) staging. grid (3, 128, 3), z:
//   z=0: K -> ws  [B,H,T,D]    z=1: V -> d_out [B,H,D,T] (transposed)
//   z=2: Q -> ws  [B,H,T,D]
// ---------------------------------------------------------------------------
__global__ __launch_bounds__(256) void gemm_qkv(
        const u16* __restrict__ X, const u16* __restrict__ Wk,
        const u16* __restrict__ Wv, const u16* __restrict__ Wq,
        u16* __restrict__ Kd, u16* __restrict__ VTd, u16* __restrict__ Qd)
{
    __shared__ u16 SMEM[17408];   // 34 KB: As(4096)+Bs(4096) | T(128x136)
    u16* As = SMEM;
    u16* Bs = SMEM + 4096;

    const int n0 = blockIdx.x * 128;
    const int m0 = blockIdx.y * 128;
    const int z  = blockIdx.z;
    const u16* W = (z == 0) ? Wk : (z == 1 ? Wv : Wq);

    const int tid  = threadIdx.x;
    const int lane = tid & 63;
    const int wv   = tid >> 6;
    const int l15  = lane & 15;
    const int q4   = lane >> 4;
    const int wm   = (wv >> 1) * 64;
    const int wn   = (wv & 1) * 64;

    f32x4 acc[4][4] = {};

    for (int kk = 0; kk < CDIM; kk += 32) {
        __syncthreads();   // previous iteration's LDS readers done
#pragma unroll
        for (int ch = 0; ch < 2; ++ch) {
            const int f = (ch * 256 + tid) * 8;   // lane's element index
            const int r = f >> 5;
            const int c = f & 31;
            const int lb = (ch * 256 + wv * 64) * 8;   // wave-uniform LDS base
            gload_lds16(X + (size_t)(m0 + r) * CDIM + kk + c, As + lb);
            gload_lds16(W + (size_t)(n0 + r) * CDIM + kk + c, Bs + lb);
        }
        __syncthreads();   // staging complete (vmcnt drained by barrier)

        short8 af[4], bf[4];
#pragma unroll
        for (int t = 0; t < 4; ++t) {
            af[t] = *(const short8*)(As + (wm + t * 16 + l15) * 32 + q4 * 8);
            bf[t] = *(const short8*)(Bs + (wn + t * 16 + l15) * 32 + q4 * 8);
        }
#pragma unroll
        for (int tm = 0; tm < 4; ++tm)
#pragma unroll
            for (int tn = 0; tn < 4; ++tn)
                acc[tm][tn] = mfma16(af[tm], bf[tn], acc[tm][tn]);
    }

    if (z != 1) {
        // ---- scatter epilogue to [B,H,T,D] ------------------------------
        u16* D = (z == 0) ? Kd : Qd;
#pragma unroll
        for (int tm = 0; tm < 4; ++tm)
#pragma unroll
            for (int tn = 0; tn < 4; ++tn) {
                const int col = n0 + wn + tn * 16 + l15;
#pragma unroll
                for (int r = 0; r < 4; ++r) {
                    const int row = m0 + wm + tm * 16 + q4 * 4 + r;
                    const int b = row >> 8, t = row & 255;
                    const int h = col >> 6, d = col & 63;
                    D[(size_t)((b * NHEAD + h) * SEQ + t) * DHEAD + d] =
                        f2b(acc[tm][tn][r]);
                }
            }
    } else {
        // ---- transpose epilogue: V^T [B,H,D,T] --------------------------
        __syncthreads();                  // all waves done with As/Bs
        u16* T = SMEM;                    // [128 feat][136]
#pragma unroll
        for (int tm = 0; tm < 4; ++tm)
#pragma unroll
            for (int tn = 0; tn < 4; ++tn) {
                const int cl = wn + tn * 16 + l15;            // feature-local
#pragma unroll
                for (int r = 0; r < 4; ++r) {
                    const int rl = wm + tm * 16 + q4 * 4 + r; // t-local
                    T[cl * 136 + rl] = f2b(acc[tm][tn][r]);
                }
            }
        __syncthreads();
        const int b  = m0 >> 8;
        const int t0 = m0 & 255;
        const int fl = tid >> 1;          // feature-local 0..127
        const int hf = tid & 1;           // which 64-t half
        const int fg = n0 + fl;
        const int h  = fg >> 6, d = fg & 63;
        u16* dst = VTd + ((size_t)(b * NHEAD + h) * DHEAD + d) * SEQ + t0 + hf * 64;
        const u16* src = T + fl * 136 + hf * 64;
#pragma unroll
        for (int j = 0; j < 8; ++j)
            *(uint4*)(dst + j * 8) = *(const uint4*)(src + j * 8);
    }
}

// ---------------------------------------------------------------------------
// Attention: block = (chunk CH, bh). 64 query rows, causal keys [0,64(CH+1)).
// Q read directly as bf16 A-frags; K staged [key][72]; V^T staged [d][136]
// coalesced. Full score row in registers; O -> ws [B,H,T,D].
// ---------------------------------------------------------------------------
template <int CH>
__device__ __forceinline__ void attn_body(
        const u16* __restrict__ Qg, const u16* __restrict__ Kg,
        const u16* __restrict__ VTg, u16* __restrict__ Og, int bh,
        u16* SA, u16* Pbuf)
{
    constexpr int NKEY = 64 * (CH + 1);
    constexpr int KT   = NKEY / 16;
    constexpr int NPH  = (NKEY + 127) / 128;

    const int tid  = threadIdx.x;
    const int wv   = tid >> 6;
    const int lane = tid & 63;
    const int l15  = lane & 15;
    const int q4   = lane >> 4;
    const int qrow0 = CH * 64 + wv * 16;
    const int qmax  = qrow0 + 15;

    short8 aq[2];
#pragma unroll
    for (int ks = 0; ks < 2; ++ks)
        aq[ks] = *(const short8*)(Qg + (size_t)(bh * SEQ + qrow0 + l15) * DHEAD
                                     + ks * 32 + q4 * 8);

    // ---- S = Q K^T * scale, causal --------------------------------------
    u16* Kbuf = SA;                      // [128][72]
    f32x4 s[KT];
#pragma unroll
    for (int ph = 0; ph < NPH; ++ph) {
        const int rows = (NKEY - ph * 128) < 128 ? (NKEY - ph * 128) : 128;
        for (int it = 0; it < rows / 32; ++it) {
            const int r  = it * 32 + (tid >> 3);
            const int d0 = (tid & 7) * 8;
            *(uint4*)(Kbuf + r * 72 + d0) =
                *(const uint4*)(Kg + (size_t)(bh * SEQ + ph * 128 + r) * DHEAD + d0);
        }
        __syncthreads();
#pragma unroll
        for (int t = 0; t < rows / 16; ++t) {
            const int gt = ph * 8 + t;
            if (gt * 16 <= qmax) {
                f32x4 z = {0.f, 0.f, 0.f, 0.f};
#pragma unroll
                for (int ks = 0; ks < 2; ++ks) {
                    short8 bk = *(const short8*)(Kbuf + (t * 16 + l15) * 72
                                                 + ks * 32 + q4 * 8);
                    z = mfma16(aq[ks], bk, z);
                }
                const int kc = gt * 16 + l15;
#pragma unroll
                for (int r = 0; r < 4; ++r) {
                    float v = z[r] * SCALE;
                    if (kc > qrow0 + q4 * 4 + r) v = -1e30f;
                    z[r] = v;
                }
                s[gt] = z;
            } else {
                f32x4 neg = {-1e30f, -1e30f, -1e30f, -1e30f};
                s[gt] = neg;
            }
        }
        __syncthreads();
    }

    // ---- softmax --------------------------------------------------------
    float mx[4], sm[4], rs[4];
#pragma unroll
    for (int r = 0; r < 4; ++r) {
        float m = -1e30f;
#pragma unroll
        for (int t = 0; t < KT; ++t) m = fmaxf(m, s[t][r]);
#pragma unroll
        for (int off = 1; off < 16; off <<= 1)
            m = fmaxf(m, __shfl_xor(m, off, 16));
        mx[r] = m;
        sm[r] = 0.f;
    }
#pragma unroll
    for (int t = 0; t < KT; ++t)
#pragma unroll
        for (int r = 0; r < 4; ++r) {
            float p = __expf(s[t][r] - mx[r]);
            s[t][r] = p;
            sm[r] += p;
        }
#pragma unroll
    for (int r = 0; r < 4; ++r) {
#pragma unroll
        for (int off = 1; off < 16; off <<= 1)
            sm[r] += __shfl_xor(sm[r], off, 16);
        rs[r] = 1.f / sm[r];
    }

    // ---- O = P V --------------------------------------------------------
    u16* Vt = SA;                        // [64 d][136]
    u16* Pw = Pbuf + wv * 16 * 40;
    f32x4 o[4] = {};
#pragma unroll
    for (int ph = 0; ph < NPH; ++ph) {
        const int rows = (NKEY - ph * 128) < 128 ? (NKEY - ph * 128) : 128;
        const int cpr  = rows >> 3;      // uint4 chunks per d-row
#pragma unroll
        for (int it = 0; it < 4; ++it) {
            if (it < cpr / 4) {
                const int flat = it * 256 + tid;
                const int rd = flat / cpr;
                const int kc = (flat - rd * cpr) * 8;
                *(uint4*)(Vt + rd * 136 + kc) =
                    *(const uint4*)(VTg + ((size_t)bh * DHEAD + rd) * SEQ
                                        + ph * 128 + kc);
            }
        }
        __syncthreads();
#pragma unroll
        for (int ks = 0; ks < rows / 32; ++ks) {
            const int gks = ph * 4 + ks;
            if (gks * 32 <= qmax) {
#pragma unroll
                for (int tt = 0; tt < 2; ++tt) {
                    const int gt = gks * 2 + tt;
#pragma unroll
                    for (int r = 0; r < 4; ++r)
                        Pw[(q4 * 4 + r) * 40 + tt * 16 + l15] = f2b(s[gt][r]);
                }
                asm volatile("s_waitcnt lgkmcnt(0)" ::: "memory");
                short8 ap = *(const short8*)(Pw + l15 * 40 + q4 * 8);
#pragma unroll
                for (int tn = 0; tn < 4; ++tn) {
                    short8 bv = *(const short8*)(Vt + (tn * 16 + l15) * 136
                                                 + ks * 32 + q4 * 8);
                    o[tn] = mfma16(ap, bv, o[tn]);
                }
            }
        }
        __syncthreads();
    }

    // ---- store O -> ws [B,H,T,D] ----------------------------------------
#pragma unroll
    for (int tn = 0; tn < 4; ++tn) {
        const int d = tn * 16 + l15;
#pragma unroll
        for (int r = 0; r < 4; ++r) {
            const int qr = qrow0 + q4 * 4 + r;
            Og[(size_t)(bh * SEQ + qr) * DHEAD + d] = f2b(o[tn][r] * rs[r]);
        }
    }
}

__global__ __launch_bounds__(256) void attn_kernel(
        const u16* __restrict__ Qg, const u16* __restrict__ Kg,
        const u16* __restrict__ VTg, u16* __restrict__ Og)
{
    __shared__ u16 SA[128 * 72];        // 18 KB, phase-aliased (Kbuf / Vt)
    __shared__ u16 Pbuf[4 * 16 * 40];   //  5 KB
    const int bh = blockIdx.y;
    switch (blockIdx.x) {
        case 0: attn_body<0>(Qg, Kg, VTg, Og, bh, SA, Pbuf); break;
        case 1: attn_body<1>(Qg, Kg, VTg, Og, bh, SA, Pbuf); break;
        case 2: attn_body<2>(Qg, Kg, VTg, Og, bh, SA, Pbuf); break;
        default: attn_body<3>(Qg, Kg, VTg, Og, bh, SA, Pbuf); break;
    }
}

// ---------------------------------------------------------------------------
// Output projection (bf16 inputs): out = O @ Wo^T + bo. O bf16 [B,H,T,D]
// (composite per-lane addresses, global_load_lds), Wo bf16, bo fp32.
// Writes fp32 row-major [16384x384].
// ---------------------------------------------------------------------------
__global__ __launch_bounds__(256) void gemm_out(
        const u16* __restrict__ O, const u16* __restrict__ Wo,
        const float* __restrict__ bias, float* __restrict__ out)
{
    __shared__ u16 As[128 * 32];
    __shared__ u16 Bs[128 * 32];

    const int n0 = blockIdx.x * 128;
    const int m0 = blockIdx.y * 128;

    const int tid  = threadIdx.x;
    const int lane = tid & 63;
    const int wv   = tid >> 6;
    const int l15  = lane & 15;
    const int q4   = lane >> 4;
    const int wm   = (wv >> 1) * 64;
    const int wn   = (wv & 1) * 64;

    f32x4 acc[4][4] = {};

    for (int kk = 0; kk < CDIM; kk += 32) {
        __syncthreads();
#pragma unroll
        for (int ch = 0; ch < 2; ++ch) {
            const int f = (ch * 256 + tid) * 8;
            const int r = f >> 5;
            const int c = f & 31;
            const int row = m0 + r;
            const int b = row >> 8, t = row & 255;
            const int k = kk + c;
            const int hh = k >> 6, dd = k & 63;
            const int lb = (ch * 256 + wv * 64) * 8;
            gload_lds16(O + (size_t)((b * NHEAD + hh) * SEQ + t) * DHEAD + dd,
                        As + lb);
            gload_lds16(Wo + (size_t)(n0 + r) * CDIM + kk + c, Bs + lb);
        }
        __syncthreads();

        short8 af[4], bf[4];
#pragma unroll
        for (int t = 0; t < 4; ++t) {
            af[t] = *(const short8*)(As + (wm + t * 16 + l15) * 32 + q4 * 8);
            bf[t] = *(const short8*)(Bs + (wn + t * 16 + l15) * 32 + q4 * 8);
        }
#pragma unroll
        for (int tm = 0; tm < 4; ++tm)
#pragma unroll
            for (int tn = 0; tn < 4; ++tn)
                acc[tm][tn] = mfma16(af[tm], bf[tn], acc[tm][tn]);
    }

#pragma unroll
    for (int tm = 0; tm < 4; ++tm) {
#pragma unroll
        for (int tn = 0; tn < 4; ++tn) {
            const int col = n0 + wn + tn * 16 + l15;
            const float bb = bias[col];
#pragma unroll
            for (int r = 0; r < 4; ++r) {
                const int row = m0 + wm + tm * 16 + q4 * 4 + r;
                out[(size_t)row * CDIM + col] = acc[tm][tn][r] + bb;  // fp32
            }
        }
    }
}

extern "C" void kernel_launch(void* const* d_in, const int* in_sizes, int n_in,
                              void* d_out, int out_size, void* d_ws, size_t ws_size,
                              hipStream_t stream)
{
    const float* x  = (const float*)d_in[0];
    const float* Wk = (const float*)d_in[1];
    const float* Wq = (const float*)d_in[2];
    const float* Wv = (const float*)d_in[3];
    const float* Wo = (const float*)d_in[4];
    const float* bo = (const float*)d_in[5];
    float* out = (float*)d_out;

    // ws layout (u16): xb + 4 weights + K + Q + O  = 51.5 MB
    // (ws_size ~256 MiB per the harness's 268 MB poison fill)
    const size_t SZ = (size_t)NROW * CDIM;   // 6,291,456
    const size_t WZ = (size_t)CDIM * CDIM;   //   147,456
    u16* xb  = (u16*)d_ws;
    u16* Wkb = xb  + SZ;
    u16* Wqb = Wkb + WZ;
    u16* Wvb = Wqb + WZ;
    u16* Wob = Wvb + WZ;
    u16* Kw  = Wob + WZ;
    u16* Qw  = Kw + SZ;
    u16* Ow  = Qw + SZ;
    u16* VTw = (u16*)d_out;   // V^T [B,H,D,T] scratch in d_out

    cvt_x<<<dim3((int)(SZ / 2048)), 256, 0, stream>>>(x, xb);
    cvt_w<<<dim3((int)(WZ / 2048), 4), 256, 0, stream>>>(
        Wk, Wq, Wv, Wo, Wkb, Wqb, Wvb, Wob);

    dim3 g1(CDIM / 128, NROW / 128, 3);
    gemm_qkv<<<g1, 256, 0, stream>>>(xb, Wkb, Wvb, Wqb, Kw, VTw, Qw);

    dim3 g2(4, BATCH * NHEAD);
    attn_kernel<<<g2, 256, 0, stream>>>(Qw, Kw, VTw, Ow);

    dim3 g3(CDIM / 128, NROW / 128);
    gemm_out<<<g3, 256, 0, stream>>>(Ow, Wob, bo, out);
}